// Round 4
// baseline (241.119 us; speedup 1.0000x reference)
//
#include <hip/hip_runtime.h>

#define B_  8
#define QL_ 128
#define ML_ 1024
#define KS_ 512
#define H_  256

// ws layout (floats):
//   Eq = exp2(2log2e * qproj): [B][QL][H]  @ 0        (262144 floats)
//   Ek = exp2(2log2e * kproj): [B][ML][H]  @ 262144   (2097152 floats)
//   mask canonical uint8 [B*ML]            @ 2359296  (8192 bytes)
#define QP_OFF 0
#define KP_OFF 262144
#define MASK_OFF 2359296

// ---------------------------------------------------------------------------
// Fused projection kernel, v2: double-buffered LDS, 2-tile-deep register
// prefetch, ONE barrier per k-tile. Flat grid of 577 blocks:
//   g 0..575: GEMM tiles over combined M (rows 0..1023 = query, rest = memory)
//     bn = (g&7)>>1 (XCD-affine W strip), bm = ((g>>3)<<1)|(g&1)  (0..143)
//   g 576   : mask canonicalizer
// out[m][n] = exp2( SC * (sum_k X[m][k]*W[n][k] + bias[n]) ), K=512, N=256.
// ---------------------------------------------------------------------------
__global__ __launch_bounds__(256) void proj_kernel(
    const float* __restrict__ query, const float* __restrict__ memory,
    const float* __restrict__ Wq, const float* __restrict__ bq,
    const float* __restrict__ Wk, const float* __restrict__ bk,
    float* __restrict__ Eq, float* __restrict__ Ek,
    const unsigned char* __restrict__ mraw, unsigned char* __restrict__ mout) {
    const int g = blockIdx.x;
    const int t = threadIdx.x;

    if (g == 576) {   // ---- mask canonicalizer ----
        __shared__ int s_not01, s_not0f;
        const unsigned int* w = (const unsigned int*)mraw;
        if (t == 0) { s_not01 = 0; s_not0f = 0; }
        __syncthreads();
        int not01 = 0, not0f = 0;
        for (int i = t; i < 2048; i += 256) {
            unsigned int v = w[i];
            if (v != 0u && v != 1u) not01 = 1;
            if (v != 0u && v != 0x3F800000u) not0f = 1;
        }
        if (not01) atomicOr(&s_not01, 1);
        if (not0f) atomicOr(&s_not0f, 1);
        __syncthreads();
        int wordTyped = (!s_not01) || (!s_not0f);
        for (int i = t; i < B_ * ML_; i += 256) {
            unsigned char mv;
            if (wordTyped) mv = (w[i] != 0u) ? 1 : 0;
            else           mv = mraw[i] ? 1 : 0;
            mout[i] = mv;
        }
        return;
    }

    const float SC = 2.885390081777926815f;   // 2*log2(e)
    const int K = 512, N = 256;
    __shared__ float Xs[2][16][68];
    __shared__ float Ws[2][16][68];

    const int bn = (g & 7) >> 1;
    const int bm = ((g >> 3) << 1) | (g & 1);

    const float *X, *W, *bias; float* out; int mrow0;
    if (bm < 16) { X = query;  W = Wq; bias = bq; out = Eq; mrow0 = bm * 64; }
    else         { X = memory; W = Wk; bias = bk; out = Ek; mrow0 = (bm - 16) * 64; }

    const int tx = t & 15, ty = t >> 4;
    const int lr = t >> 2;           // staged row 0..63
    const int lk = (t & 3) << 2;     // staged k offset {0,4,8,12}
    const float* Xrow = X + (size_t)(mrow0 + lr) * K + lk;
    const float* Wrow = W + (size_t)(bn * 64 + lr) * K + lk;

    float4 xa[2], wa[2];
    xa[0] = *(const float4*)(Xrow);       wa[0] = *(const float4*)(Wrow);
    xa[1] = *(const float4*)(Xrow + 16);  wa[1] = *(const float4*)(Wrow + 16);

    // write tile 0 -> buf 0
    Xs[0][lk + 0][lr] = xa[0].x; Xs[0][lk + 1][lr] = xa[0].y;
    Xs[0][lk + 2][lr] = xa[0].z; Xs[0][lk + 3][lr] = xa[0].w;
    Ws[0][lk + 0][lr] = wa[0].x; Ws[0][lk + 1][lr] = wa[0].y;
    Ws[0][lk + 2][lr] = wa[0].z; Ws[0][lk + 3][lr] = wa[0].w;
    __syncthreads();

    float acc[4][4] = {};
    for (int kt = 0; kt < 32; ++kt) {
        const int cur = kt & 1;
        // issue loads for tile kt+2 (regs for tile kt were consumed last iter)
        if (kt + 2 < 32) {
            xa[cur] = *(const float4*)(Xrow + (kt + 2) * 16);
            wa[cur] = *(const float4*)(Wrow + (kt + 2) * 16);
        }
        // compute tile kt from buf[cur] (covers in-flight load latency)
#pragma unroll
        for (int k = 0; k < 16; ++k) {
            float4 av = *(const float4*)(&Xs[cur][k][ty * 4]);
            float4 bv = *(const float4*)(&Ws[cur][k][tx * 4]);
            float a[4] = {av.x, av.y, av.z, av.w};
            float b[4] = {bv.x, bv.y, bv.z, bv.w};
#pragma unroll
            for (int i = 0; i < 4; ++i)
#pragma unroll
                for (int j = 0; j < 4; ++j)
                    acc[i][j] = fmaf(a[i], b[j], acc[i][j]);
        }
        // write tile kt+1 (loaded 2 iters ago) -> other buffer; one barrier
        if (kt + 1 < 32) {
            const int nxt = cur ^ 1;
            Xs[nxt][lk + 0][lr] = xa[nxt].x; Xs[nxt][lk + 1][lr] = xa[nxt].y;
            Xs[nxt][lk + 2][lr] = xa[nxt].z; Xs[nxt][lk + 3][lr] = xa[nxt].w;
            Ws[nxt][lk + 0][lr] = wa[nxt].x; Ws[nxt][lk + 1][lr] = wa[nxt].y;
            Ws[nxt][lk + 2][lr] = wa[nxt].z; Ws[nxt][lk + 3][lr] = wa[nxt].w;
            __syncthreads();
        }
    }

    float4 bv = *(const float4*)(bias + bn * 64 + tx * 4);
    float bvec[4] = {bv.x, bv.y, bv.z, bv.w};
#pragma unroll
    for (int i = 0; i < 4; ++i) {
        int m = mrow0 + ty * 4 + i;
        float4 o;
        o.x = __builtin_amdgcn_exp2f(SC * (acc[i][0] + bvec[0]));
        o.y = __builtin_amdgcn_exp2f(SC * (acc[i][1] + bvec[1]));
        o.z = __builtin_amdgcn_exp2f(SC * (acc[i][2] + bvec[2]));
        o.w = __builtin_amdgcn_exp2f(SC * (acc[i][3] + bvec[3]));
        *(float4*)(out + (size_t)m * N + bn * 64 + tx * 4) = o;
    }
}

// ---------------------------------------------------------------------------
// Fused logits + masked softmax. Block = (b, q-pair): owns 2 FULL m-rows.
//   sr[q][m] = sum_h wl[h] / (Eq[q][h]*Ek[m][h] + 1)   (tanh+exp folded)
//   weights[q][m] = softmax_m( -2*sr, masked -> 0 )    (shift-invariant form)
// Thread: q = q0 + (tid>>7), m = mt*128 + (tid&127), mt = 0..7 (acc -> LDS).
// 4-way reciprocal grouping: 1 v_rcp per 4 h. Grid 512 blocks = 2/CU even;
// b = bid&7 for XCD L2 affinity on Ek[b] (1 MB).
// ---------------------------------------------------------------------------
__global__ __launch_bounds__(256) void logits_sm_kernel(
    const float* __restrict__ Eq, const float* __restrict__ Ek,
    const float* __restrict__ wl, const unsigned char* __restrict__ mcan,
    float* __restrict__ wout) {
    const int bid = blockIdx.x;
    const int b   = bid & 7;
    const int q0  = (bid >> 3) * 2;     // q-pair base
    const int tid = threadIdx.x;
    const int qi   = tid >> 7;          // 0/1
    const int mloc = tid & 127;

    __shared__ float eqs[2][256];
    __shared__ float wls[256];
    __shared__ float kq[4][128][4];     // one 16-h chunk of a 128-m tile
    __shared__ float accs[8][256];
    __shared__ unsigned int msksw[256];
    __shared__ float redm[4];

    // one-time stages
    if (tid < 128)
        *(float4*)(&eqs[tid >> 6][(tid & 63) * 4]) =
            *(const float4*)(Eq + ((size_t)(b * QL_ + q0 + (tid >> 6))) * H_ + (tid & 63) * 4);
    else if (tid < 192)
        *(float4*)(&wls[(tid - 128) * 4]) = *(const float4*)(wl + (tid - 128) * 4);
    msksw[tid] = ((const unsigned int*)(mcan + b * ML_))[tid];

    const float* kbase = Ek + (size_t)(b * ML_) * H_;
    const int srow = tid & 127;
    const int sq2  = tid >> 7;

    float4 a0 = *(const float4*)(kbase + (size_t)srow * H_ + 8 * sq2);
    float4 a1 = *(const float4*)(kbase + (size_t)srow * H_ + 8 * sq2 + 4);

    for (int mt = 0; mt < 8; ++mt) {
        float acc = 0.f;
        for (int c = 0; c < 16; ++c) {
            __syncthreads();
            *(float4*)(&kq[2 * sq2 + 0][srow][0]) = a0;
            *(float4*)(&kq[2 * sq2 + 1][srow][0]) = a1;
            __syncthreads();
            // prefetch next (mt,c) step
            int s1 = mt * 16 + c + 1;
            if (s1 < 128) {
                int pm = s1 >> 4, pc = s1 & 15;
                const float* ka = kbase + (size_t)(pm * 128 + srow) * H_ + pc * 16 + 8 * sq2;
                a0 = *(const float4*)(ka);
                a1 = *(const float4*)(ka + 4);
            }
            const int h0 = c * 16;
#pragma unroll
            for (int quad = 0; quad < 4; ++quad) {
                float4 k4 = *(const float4*)(&kq[quad][mloc][0]);
                float4 w4 = *(const float4*)(&wls[h0 + quad * 4]);
                float4 q4 = *(const float4*)(&eqs[qi][h0 + quad * 4]);
                float p0 = fmaf(k4.x, q4.x, 1.0f);
                float p1 = fmaf(k4.y, q4.y, 1.0f);
                float p2 = fmaf(k4.z, q4.z, 1.0f);
                float p3 = fmaf(k4.w, q4.w, 1.0f);
                float p01 = p0 * p1, p23 = p2 * p3;
                float n01 = fmaf(w4.y, p0, w4.x * p1);
                float n23 = fmaf(w4.w, p2, w4.z * p3);
                float Nm  = fmaf(n23, p01, n01 * p23);
                float P   = p01 * p23;
                acc = fmaf(Nm, __builtin_amdgcn_rcpf(P), acc);
            }
        }
        accs[mt][tid] = acc;
    }
    __syncthreads();

    // ---- masked softmax over the 1024 m's of row q (owned by 128 threads) ----
    const unsigned char* mrow = (const unsigned char*)msksw;
    float l[8];
    unsigned int mbits = 0;
    float mx = -3.0e38f;
#pragma unroll
    for (int mt = 0; mt < 8; ++mt) {
        float v = accs[mt][tid];
        int mk = mrow[mt * 128 + mloc];
        mbits |= (unsigned)(mk != 0) << mt;
        l[mt] = mk ? -3.0e38f : (-2.0f * v);
        mx = fmaxf(mx, l[mt]);
    }
#pragma unroll
    for (int off = 32; off >= 1; off >>= 1)
        mx = fmaxf(mx, __shfl_xor(mx, off));
    if ((tid & 63) == 0) redm[tid >> 6] = mx;
    __syncthreads();
    mx = fmaxf(redm[qi * 2], redm[qi * 2 + 1]);
    __syncthreads();

    const float L2E = 1.44269504088896340736f;
    float e[8], s = 0.f;
#pragma unroll
    for (int mt = 0; mt < 8; ++mt) {
        e[mt] = ((mbits >> mt) & 1) ? 0.f
                : __builtin_amdgcn_exp2f((l[mt] - mx) * L2E);
        s += e[mt];
    }
#pragma unroll
    for (int off = 32; off >= 1; off >>= 1)
        s += __shfl_xor(s, off);
    if ((tid & 63) == 0) redm[tid >> 6] = s;
    __syncthreads();
    s = redm[qi * 2] + redm[qi * 2 + 1];
    float inv = __builtin_amdgcn_rcpf(s);

    float* wrow = wout + ((size_t)(b * QL_ + q0 + qi)) * ML_;
#pragma unroll
    for (int mt = 0; mt < 8; ++mt)
        wrow[mt * 128 + mloc] = e[mt] * inv;
}

// ---------------------------------------------------------------------------
// attns[b] = W[b] (128x1024) @ M[b] (1024x512). LDS-tiled GEMM (unchanged).
// ---------------------------------------------------------------------------
__global__ __launch_bounds__(256) void attn_out_kernel(
    const float* __restrict__ wgt, const float* __restrict__ mem,
    float* __restrict__ out) {
    const int bid = blockIdx.x;
    const int b  = bid & 7;
    const int j2 = bid >> 3;
    const int mt = j2 & 3;
    const int nt = j2 >> 2;
    const int t = threadIdx.x;
    __shared__ float As[32][34];
    __shared__ float Bs[32][64];

    const int ar = t >> 3, ac = (t & 7) << 2;
    const int br = t >> 4, bc = (t & 15) << 2;
    const float* Ap = wgt + ((size_t)(b * QL_ + mt * 32 + ar)) * ML_ + ac;
    const float* Bp = mem + ((size_t)(b * ML_ + br)) * KS_ + nt * 64 + bc;

    const int tx = t & 15, ty = t >> 4;
    float acc0[4] = {0.f, 0.f, 0.f, 0.f};
    float acc1[4] = {0.f, 0.f, 0.f, 0.f};

    float4 apre = *(const float4*)(Ap);
    float4 bpre0 = *(const float4*)(Bp);
    float4 bpre1 = *(const float4*)(Bp + (size_t)16 * KS_);

    for (int k0 = 0; k0 < ML_; k0 += 32) {
        __syncthreads();
        As[ac + 0][ar] = apre.x; As[ac + 1][ar] = apre.y;
        As[ac + 2][ar] = apre.z; As[ac + 3][ar] = apre.w;
        *(float4*)(&Bs[br][bc])      = bpre0;
        *(float4*)(&Bs[br + 16][bc]) = bpre1;
        __syncthreads();
        if (k0 + 32 < ML_) {
            apre  = *(const float4*)(Ap + k0 + 32);
            bpre0 = *(const float4*)(Bp + (size_t)(k0 + 32) * KS_);
            bpre1 = *(const float4*)(Bp + (size_t)(k0 + 48) * KS_);
        }
#pragma unroll
        for (int kk = 0; kk < 32; ++kk) {
            float2 a2 = *(const float2*)(&As[kk][ty * 2]);
            float4 b4 = *(const float4*)(&Bs[kk][tx * 4]);
            acc0[0] = fmaf(a2.x, b4.x, acc0[0]);
            acc0[1] = fmaf(a2.x, b4.y, acc0[1]);
            acc0[2] = fmaf(a2.x, b4.z, acc0[2]);
            acc0[3] = fmaf(a2.x, b4.w, acc0[3]);
            acc1[0] = fmaf(a2.y, b4.x, acc1[0]);
            acc1[1] = fmaf(a2.y, b4.y, acc1[1]);
            acc1[2] = fmaf(a2.y, b4.z, acc1[2]);
            acc1[3] = fmaf(a2.y, b4.w, acc1[3]);
        }
    }
    size_t orow = ((size_t)(b * QL_ + mt * 32 + ty * 2)) * KS_ + nt * 64 + tx * 4;
    *(float4*)(out + orow)       = make_float4(acc0[0], acc0[1], acc0[2], acc0[3]);
    *(float4*)(out + orow + KS_) = make_float4(acc1[0], acc1[1], acc1[2], acc1[3]);
}

extern "C" void kernel_launch(void* const* d_in, const int* in_sizes, int n_in,
                              void* d_out, int out_size, void* d_ws, size_t ws_size,
                              hipStream_t stream) {
    const float* query  = (const float*)d_in[0];
    const float* memory = (const float*)d_in[1];
    const unsigned char* mask = (const unsigned char*)d_in[2];
    const float* Wq = (const float*)d_in[3];
    const float* bq = (const float*)d_in[4];
    const float* Wk = (const float*)d_in[5];
    const float* bk = (const float*)d_in[6];
    const float* wl = (const float*)d_in[7];
    // d_in[8] (bl) cancels under softmax shift-invariance; not read.

    float* ws = (float*)d_ws;
    float* Eq = ws + QP_OFF;
    float* Ek = ws + KP_OFF;
    unsigned char* mcan = (unsigned char*)(ws + MASK_OFF);

    float* attns = (float*)d_out;                      // [B][QL][KS]
    float* wout  = (float*)d_out + B_ * QL_ * KS_;     // [B][QL][ML] final weights

    proj_kernel<<<dim3(577), dim3(256), 0, stream>>>(query, memory, Wq, bq, Wk, bk,
                                                     Eq, Ek, mask, mcan);
    logits_sm_kernel<<<dim3(512), dim3(256), 0, stream>>>(Eq, Ek, wl, mcan, wout);
    attn_out_kernel<<<dim3(256), dim3(256), 0, stream>>>(wout, memory, attns);
}

// Round 5
// 234.715 us; speedup vs baseline: 1.0273x; 1.0273x over previous
//
#include <hip/hip_runtime.h>

#define B_  8
#define QL_ 128
#define ML_ 1024
#define KS_ 512
#define H_  256

// ws layout (floats):
//   Eq = exp2(2log2e * qproj): [B][QL][H]  @ 0        (262144 floats)
//   Ek = exp2(2log2e * kproj): [B][ML][H]  @ 262144   (2097152 floats)
//   mask canonical uint8 [B*ML]            @ 2359296  (8192 bytes = 2048 floats)
//   psum [B*QL][8] partial row sums        @ 2361344  (8192 floats)
#define QP_OFF 0
#define KP_OFF 262144
#define MASK_OFF 2359296
#define PSUM_OFF 2361344

// ---------------------------------------------------------------------------
// Fused projection kernel, v3: BK=32 double-buffered LDS (16 barriers),
// 2-tile-deep register prefetch (~2000 cy load->LDS-write gap > HBM latency).
// Flat grid of 577 blocks: g 0..575 GEMM tiles (M = 1024 query + 8192 memory
// rows), g 576 mask canonicalizer.
// out[m][n] = exp2( SC * (sum_k X[m][k]*W[n][k] + bias[n]) ), K=512, N=256.
// ---------------------------------------------------------------------------
__global__ __launch_bounds__(256) void proj_kernel(
    const float* __restrict__ query, const float* __restrict__ memory,
    const float* __restrict__ Wq, const float* __restrict__ bq,
    const float* __restrict__ Wk, const float* __restrict__ bk,
    float* __restrict__ Eq, float* __restrict__ Ek,
    const unsigned char* __restrict__ mraw, unsigned char* __restrict__ mout) {
    const int g = blockIdx.x;
    const int t = threadIdx.x;

    if (g == 576) {   // ---- mask canonicalizer ----
        __shared__ int s_not01, s_not0f;
        const unsigned int* w = (const unsigned int*)mraw;
        if (t == 0) { s_not01 = 0; s_not0f = 0; }
        __syncthreads();
        int not01 = 0, not0f = 0;
        for (int i = t; i < 2048; i += 256) {
            unsigned int v = w[i];
            if (v != 0u && v != 1u) not01 = 1;
            if (v != 0u && v != 0x3F800000u) not0f = 1;
        }
        if (not01) atomicOr(&s_not01, 1);
        if (not0f) atomicOr(&s_not0f, 1);
        __syncthreads();
        int wordTyped = (!s_not01) || (!s_not0f);
        for (int i = t; i < B_ * ML_; i += 256) {
            unsigned char mv;
            if (wordTyped) mv = (w[i] != 0u) ? 1 : 0;
            else           mv = mraw[i] ? 1 : 0;
            mout[i] = mv;
        }
        return;
    }

    const float SC = 2.885390081777926815f;   // 2*log2(e)
    const int K = 512, N = 256;
    __shared__ float Xs[2][32][68];
    __shared__ float Ws[2][32][68];

    const int bn = (g & 7) >> 1;
    const int bm = ((g >> 3) << 1) | (g & 1);

    const float *X, *W, *bias; float* out; int mrow0;
    if (bm < 16) { X = query;  W = Wq; bias = bq; out = Eq; mrow0 = bm * 64; }
    else         { X = memory; W = Wk; bias = bk; out = Ek; mrow0 = (bm - 16) * 64; }

    const int tx = t & 15, ty = t >> 4;
    const int lr = t >> 2;           // staged row 0..63
    const int lk = (t & 3) << 2;     // staged k offset {0,4,8,12}
    const float* Xrow = X + (size_t)(mrow0 + lr) * K + lk;
    const float* Wrow = W + (size_t)(bn * 64 + lr) * K + lk;

    // 2 register slots, each holding one 32-k tile (2 float4 per array)
    float4 xsl[2][2], wsl[2][2];
    xsl[0][0] = *(const float4*)(Xrow);      xsl[0][1] = *(const float4*)(Xrow + 16);
    wsl[0][0] = *(const float4*)(Wrow);      wsl[0][1] = *(const float4*)(Wrow + 16);
    xsl[1][0] = *(const float4*)(Xrow + 32); xsl[1][1] = *(const float4*)(Xrow + 48);
    wsl[1][0] = *(const float4*)(Wrow + 32); wsl[1][1] = *(const float4*)(Wrow + 48);

    // write tile 0 (slot 0) -> buf 0
    Xs[0][lk + 0][lr] = xsl[0][0].x; Xs[0][lk + 1][lr] = xsl[0][0].y;
    Xs[0][lk + 2][lr] = xsl[0][0].z; Xs[0][lk + 3][lr] = xsl[0][0].w;
    Xs[0][lk + 16][lr] = xsl[0][1].x; Xs[0][lk + 17][lr] = xsl[0][1].y;
    Xs[0][lk + 18][lr] = xsl[0][1].z; Xs[0][lk + 19][lr] = xsl[0][1].w;
    Ws[0][lk + 0][lr] = wsl[0][0].x; Ws[0][lk + 1][lr] = wsl[0][0].y;
    Ws[0][lk + 2][lr] = wsl[0][0].z; Ws[0][lk + 3][lr] = wsl[0][0].w;
    Ws[0][lk + 16][lr] = wsl[0][1].x; Ws[0][lk + 17][lr] = wsl[0][1].y;
    Ws[0][lk + 18][lr] = wsl[0][1].z; Ws[0][lk + 19][lr] = wsl[0][1].w;
    __syncthreads();

    float acc[4][4] = {};
    for (int kt = 0; kt < 16; ++kt) {
        const int cur = kt & 1;
        // issue loads for tile kt+2 into slot cur (its tile kt is already in LDS)
        if (kt + 2 < 16) {
            const int o = (kt + 2) * 32;
            xsl[cur][0] = *(const float4*)(Xrow + o);
            xsl[cur][1] = *(const float4*)(Xrow + o + 16);
            wsl[cur][0] = *(const float4*)(Wrow + o);
            wsl[cur][1] = *(const float4*)(Wrow + o + 16);
        }
        // compute tile kt from buf[cur]
#pragma unroll
        for (int k = 0; k < 32; ++k) {
            float4 av = *(const float4*)(&Xs[cur][k][ty * 4]);
            float4 bv = *(const float4*)(&Ws[cur][k][tx * 4]);
            float a[4] = {av.x, av.y, av.z, av.w};
            float b[4] = {bv.x, bv.y, bv.z, bv.w};
#pragma unroll
            for (int i = 0; i < 4; ++i)
#pragma unroll
                for (int j = 0; j < 4; ++j)
                    acc[i][j] = fmaf(a[i], b[j], acc[i][j]);
        }
        // write tile kt+1 (slot cur^1, loaded 2 iters ago) -> buf cur^1
        if (kt + 1 < 16) {
            const int nxt = cur ^ 1;
            Xs[nxt][lk + 0][lr] = xsl[nxt][0].x; Xs[nxt][lk + 1][lr] = xsl[nxt][0].y;
            Xs[nxt][lk + 2][lr] = xsl[nxt][0].z; Xs[nxt][lk + 3][lr] = xsl[nxt][0].w;
            Xs[nxt][lk + 16][lr] = xsl[nxt][1].x; Xs[nxt][lk + 17][lr] = xsl[nxt][1].y;
            Xs[nxt][lk + 18][lr] = xsl[nxt][1].z; Xs[nxt][lk + 19][lr] = xsl[nxt][1].w;
            Ws[nxt][lk + 0][lr] = wsl[nxt][0].x; Ws[nxt][lk + 1][lr] = wsl[nxt][0].y;
            Ws[nxt][lk + 2][lr] = wsl[nxt][0].z; Ws[nxt][lk + 3][lr] = wsl[nxt][0].w;
            Ws[nxt][lk + 16][lr] = wsl[nxt][1].x; Ws[nxt][lk + 17][lr] = wsl[nxt][1].y;
            Ws[nxt][lk + 18][lr] = wsl[nxt][1].z; Ws[nxt][lk + 19][lr] = wsl[nxt][1].w;
            __syncthreads();
        }
    }

    float4 bv = *(const float4*)(bias + bn * 64 + tx * 4);
    float bvec[4] = {bv.x, bv.y, bv.z, bv.w};
#pragma unroll
    for (int i = 0; i < 4; ++i) {
        int m = mrow0 + ty * 4 + i;
        float4 o;
        o.x = __builtin_amdgcn_exp2f(SC * (acc[i][0] + bvec[0]));
        o.y = __builtin_amdgcn_exp2f(SC * (acc[i][1] + bvec[1]));
        o.z = __builtin_amdgcn_exp2f(SC * (acc[i][2] + bvec[2]));
        o.w = __builtin_amdgcn_exp2f(SC * (acc[i][3] + bvec[3]));
        *(float4*)(out + (size_t)m * N + bn * 64 + tx * 4) = o;
    }
}

// ---------------------------------------------------------------------------
// Logits v3 (R3 tiling + no-max softmax prep):
//   sr[q][m]   = sum_h wl[h] / (Eq[q][h]*Ek[m][h] + 1)
//   u[q][m]    = mask[m] ? 0 : exp2(-2*log2e * sr)      (bounded, fp32-safe;
//                shift-invariance => identical to reference after normalize)
//   psum[row][mt] = partial row-sum of u over this block's 128-m strip.
// Block = (b, q-octet, m-tile of 128); thread: m = tid&127, 4 q's (qh=tid>>7).
// kq double-buffered -> ONE barrier per 16-h chunk. Grid 1024 = 4 blocks/CU.
// ---------------------------------------------------------------------------
__global__ __launch_bounds__(256) void logits_kernel(
    const float* __restrict__ Eq, const float* __restrict__ Ek,
    const float* __restrict__ wl, const unsigned char* __restrict__ mcan,
    float* __restrict__ wout, float* __restrict__ psum) {
    const int bid = blockIdx.x;
    const int b  = bid & 7;
    const int r2 = bid >> 3;
    const int mt = r2 & 7;      // m tile of 128
    const int qt = r2 >> 3;     // q octet
    const int tid = threadIdx.x;
    const int m  = tid & 127;
    const int qh = tid >> 7;    // 0/1: which 4 q's

    __shared__ float eqs[2048];        // [j][h], j<8
    __shared__ float wls[256];
    __shared__ float kq[2][4][128][4]; // double-buffered 16-h chunk
    __shared__ float sred[4][4];       // [wave][j2]

    const float* qpb = Eq + ((size_t)(b * QL_ + qt * 8)) * H_;
    const float* kpb = Ek + ((size_t)(b * ML_ + mt * 128)) * H_;

    // one-time stage: Eq tile + wl
    *(float4*)(&eqs[tid * 4])        = *(const float4*)(qpb + tid * 4);
    *(float4*)(&eqs[1024 + tid * 4]) = *(const float4*)(qpb + 1024 + tid * 4);
    if (tid < 64) *(float4*)(&wls[tid * 4]) = *(const float4*)(wl + tid * 4);

    const float* kst = kpb + (size_t)m * H_ + 8 * qh;  // lane stages row m, 8 h
    float4 a0 = *(const float4*)(kst);
    float4 a1 = *(const float4*)(kst + 4);
    *(float4*)(&kq[0][2 * qh + 0][m][0]) = a0;
    *(float4*)(&kq[0][2 * qh + 1][m][0]) = a1;
    __syncthreads();

    float acc[4] = {0.f, 0.f, 0.f, 0.f};

    for (int c = 0; c < 16; ++c) {
        if (c < 15) {
            a0 = *(const float4*)(kst + (c + 1) * 16);
            a1 = *(const float4*)(kst + (c + 1) * 16 + 4);
        }
        const int buf = c & 1;
        const int h0 = c * 16;
#pragma unroll
        for (int quad = 0; quad < 4; ++quad) {
            float4 k4 = *(const float4*)(&kq[buf][quad][m][0]);
            float4 w4 = *(const float4*)(&wls[h0 + quad * 4]);
#pragma unroll
            for (int j2 = 0; j2 < 4; ++j2) {
                float4 q4 = *(const float4*)(&eqs[(qh * 4 + j2) * 256 + h0 + quad * 4]);
                float p0 = fmaf(k4.x, q4.x, 1.0f);
                float p1 = fmaf(k4.y, q4.y, 1.0f);
                float p2 = fmaf(k4.z, q4.z, 1.0f);
                float p3 = fmaf(k4.w, q4.w, 1.0f);
                float p01 = p0 * p1, p23 = p2 * p3;
                float n01 = fmaf(w4.y, p0, w4.x * p1);
                float n23 = fmaf(w4.w, p2, w4.z * p3);
                float Nm  = fmaf(n23, p01, n01 * p23);
                float P   = p01 * p23;
                acc[j2] = fmaf(Nm, __builtin_amdgcn_rcpf(P), acc[j2]);
            }
        }
        if (c < 15) {
            *(float4*)(&kq[buf ^ 1][2 * qh + 0][m][0]) = a0;
            *(float4*)(&kq[buf ^ 1][2 * qh + 1][m][0]) = a1;
            __syncthreads();
        }
    }

    // u = exp2(-2*log2e * sr), masked -> 0 (mask depends only on m)
    const float N2L = -2.885390081777926815f;   // -2*log2(e)
    const int mk = mcan[b * ML_ + mt * 128 + m];
    float u[4];
#pragma unroll
    for (int j2 = 0; j2 < 4; ++j2) {
        u[j2] = mk ? 0.f : __builtin_amdgcn_exp2f(N2L * acc[j2]);
        wout[((size_t)(b * QL_ + qt * 8 + qh * 4 + j2)) * ML_ + mt * 128 + m] = u[j2];
    }

    // partial row sums over this 128-m strip (deterministic, no atomics)
    float r[4] = {u[0], u[1], u[2], u[3]};
#pragma unroll
    for (int off = 32; off >= 1; off >>= 1) {
#pragma unroll
        for (int j2 = 0; j2 < 4; ++j2)
            r[j2] += __shfl_xor(r[j2], off);
    }
    if ((tid & 63) == 0) {
#pragma unroll
        for (int j2 = 0; j2 < 4; ++j2)
            sred[tid >> 6][j2] = r[j2];
    }
    __syncthreads();
    if (tid < 8) {
        const int q = tid;
        float v = sred[(q >> 2) * 2][q & 3] + sred[(q >> 2) * 2 + 1][q & 3];
        psum[((size_t)(b * QL_ + qt * 8 + q)) * 8 + mt] = v;
    }
}

// ---------------------------------------------------------------------------
// attns[b] = (u[b] @ M[b]) * inv_rowsum. LDS-tiled GEMM, epilogue-normalized.
// ---------------------------------------------------------------------------
__global__ __launch_bounds__(256) void attn_out_kernel(
    const float* __restrict__ wgt, const float* __restrict__ mem,
    const float* __restrict__ psum, float* __restrict__ out) {
    const int bid = blockIdx.x;
    const int b  = bid & 7;
    const int j2 = bid >> 3;
    const int mt = j2 & 3;
    const int nt = j2 >> 2;
    const int t = threadIdx.x;
    __shared__ float As[32][34];
    __shared__ float Bs[32][64];

    const int ar = t >> 3, ac = (t & 7) << 2;
    const int br = t >> 4, bc = (t & 15) << 2;
    const float* Ap = wgt + ((size_t)(b * QL_ + mt * 32 + ar)) * ML_ + ac;
    const float* Bp = mem + ((size_t)(b * ML_ + br)) * KS_ + nt * 64 + bc;

    const int tx = t & 15, ty = t >> 4;
    float acc0[4] = {0.f, 0.f, 0.f, 0.f};
    float acc1[4] = {0.f, 0.f, 0.f, 0.f};

    float4 apre = *(const float4*)(Ap);
    float4 bpre0 = *(const float4*)(Bp);
    float4 bpre1 = *(const float4*)(Bp + (size_t)16 * KS_);

    for (int k0 = 0; k0 < ML_; k0 += 32) {
        __syncthreads();
        As[ac + 0][ar] = apre.x; As[ac + 1][ar] = apre.y;
        As[ac + 2][ar] = apre.z; As[ac + 3][ar] = apre.w;
        *(float4*)(&Bs[br][bc])      = bpre0;
        *(float4*)(&Bs[br + 16][bc]) = bpre1;
        __syncthreads();
        if (k0 + 32 < ML_) {
            apre  = *(const float4*)(Ap + k0 + 32);
            bpre0 = *(const float4*)(Bp + (size_t)(k0 + 32) * KS_);
            bpre1 = *(const float4*)(Bp + (size_t)(k0 + 48) * KS_);
        }
#pragma unroll
        for (int kk = 0; kk < 32; ++kk) {
            float2 a2 = *(const float2*)(&As[kk][ty * 2]);
            float4 b4 = *(const float4*)(&Bs[kk][tx * 4]);
            acc0[0] = fmaf(a2.x, b4.x, acc0[0]);
            acc0[1] = fmaf(a2.x, b4.y, acc0[1]);
            acc0[2] = fmaf(a2.x, b4.z, acc0[2]);
            acc0[3] = fmaf(a2.x, b4.w, acc0[3]);
            acc1[0] = fmaf(a2.y, b4.x, acc1[0]);
            acc1[1] = fmaf(a2.y, b4.y, acc1[1]);
            acc1[2] = fmaf(a2.y, b4.z, acc1[2]);
            acc1[3] = fmaf(a2.y, b4.w, acc1[3]);
        }
    }
    // epilogue: normalize by row sums (8 partials per row, block-uniform rows)
    const float* ps = psum + ((size_t)(b * QL_ + mt * 32 + ty * 2)) * 8;
    float rs0 = 0.f, rs1 = 0.f;
#pragma unroll
    for (int i = 0; i < 8; ++i) { rs0 += ps[i]; rs1 += ps[8 + i]; }
    float inv0 = __builtin_amdgcn_rcpf(rs0);
    float inv1 = __builtin_amdgcn_rcpf(rs1);

    size_t orow = ((size_t)(b * QL_ + mt * 32 + ty * 2)) * KS_ + nt * 64 + tx * 4;
    *(float4*)(out + orow)       = make_float4(acc0[0] * inv0, acc0[1] * inv0,
                                               acc0[2] * inv0, acc0[3] * inv0);
    *(float4*)(out + orow + KS_) = make_float4(acc1[0] * inv1, acc1[1] * inv1,
                                               acc1[2] * inv1, acc1[3] * inv1);
}

// ---------------------------------------------------------------------------
// Normalize the weights output in place (runs AFTER attn_out consumed u).
// ---------------------------------------------------------------------------
__global__ __launch_bounds__(256) void scale_weights(
    float* __restrict__ wout, const float* __restrict__ psum) {
    const int row = blockIdx.x;          // b*QL + q
    const int tid = threadIdx.x;
    const float* ps = psum + (size_t)row * 8;
    float rs = ((ps[0] + ps[1]) + (ps[2] + ps[3])) +
               ((ps[4] + ps[5]) + (ps[6] + ps[7]));
    float inv = __builtin_amdgcn_rcpf(rs);
    float4* p = (float4*)(wout + (size_t)row * ML_ + tid * 4);
    float4 v = *p;
    *p = make_float4(v.x * inv, v.y * inv, v.z * inv, v.w * inv);
}

extern "C" void kernel_launch(void* const* d_in, const int* in_sizes, int n_in,
                              void* d_out, int out_size, void* d_ws, size_t ws_size,
                              hipStream_t stream) {
    const float* query  = (const float*)d_in[0];
    const float* memory = (const float*)d_in[1];
    const unsigned char* mask = (const unsigned char*)d_in[2];
    const float* Wq = (const float*)d_in[3];
    const float* bq = (const float*)d_in[4];
    const float* Wk = (const float*)d_in[5];
    const float* bk = (const float*)d_in[6];
    const float* wl = (const float*)d_in[7];
    // d_in[8] (bl) cancels under softmax shift-invariance; not read.

    float* ws = (float*)d_ws;
    float* Eq = ws + QP_OFF;
    float* Ek = ws + KP_OFF;
    unsigned char* mcan = (unsigned char*)(ws + MASK_OFF);
    float* psum = ws + PSUM_OFF;

    float* attns = (float*)d_out;                      // [B][QL][KS]
    float* wout  = (float*)d_out + B_ * QL_ * KS_;     // [B][QL][ML]: u, then weights

    proj_kernel<<<dim3(577), dim3(256), 0, stream>>>(query, memory, Wq, bq, Wk, bk,
                                                     Eq, Ek, mask, mcan);
    logits_kernel<<<dim3(1024), dim3(256), 0, stream>>>(Eq, Ek, wl, mcan, wout, psum);
    attn_out_kernel<<<dim3(256), dim3(256), 0, stream>>>(wout, memory, psum, attns);
    scale_weights<<<dim3(B_ * QL_), dim3(256), 0, stream>>>(wout, psum);
}

// Round 6
// 230.578 us; speedup vs baseline: 1.0457x; 1.0179x over previous
//
#include <hip/hip_runtime.h>

#define B_  8
#define QL_ 128
#define ML_ 1024
#define KS_ 512
#define H_  256

// ws layout (floats):
//   Eq = exp2(2log2e * qproj): [B][QL][H]  @ 0        (262144 floats)
//   Ek = exp2(2log2e * kproj): [B][ML][H]  @ 262144   (2097152 floats)
//   mask canonical uint8 [B*ML]            @ 2359296  (8192 bytes = 2048 floats)
//   psum [B*QL][8] partial row sums        @ 2361344  (8192 floats)
#define QP_OFF 0
#define KP_OFF 262144
#define MASK_OFF 2359296
#define PSUM_OFF 2361344

// ---------------------------------------------------------------------------
// Fused projection kernel, v4: BK=32 double-buffered LDS (16 barriers),
// 2-tile-deep register prefetch with NAMED registers (no dynamically-indexed
// arrays -> no scratch spill; R5's 144 MB WRITE_SIZE was exactly this spill).
// K-loop manually unrolled x2 so all LDS buffer indices are compile-time.
// Flat grid of 577 blocks: g 0..575 GEMM tiles (M = 1024 query + 8192 memory
// rows), g 576 mask canonicalizer.
// out[m][n] = exp2( SC * (sum_k X[m][k]*W[n][k] + bias[n]) ), K=512, N=256.
// ---------------------------------------------------------------------------
#define STAGE(BUF, XA, XB, WA, WB) do { \
    Xs[BUF][lk + 0][lr] = (XA).x; Xs[BUF][lk + 1][lr] = (XA).y; \
    Xs[BUF][lk + 2][lr] = (XA).z; Xs[BUF][lk + 3][lr] = (XA).w; \
    Xs[BUF][lk +16][lr] = (XB).x; Xs[BUF][lk +17][lr] = (XB).y; \
    Xs[BUF][lk +18][lr] = (XB).z; Xs[BUF][lk +19][lr] = (XB).w; \
    Ws[BUF][lk + 0][lr] = (WA).x; Ws[BUF][lk + 1][lr] = (WA).y; \
    Ws[BUF][lk + 2][lr] = (WA).z; Ws[BUF][lk + 3][lr] = (WA).w; \
    Ws[BUF][lk +16][lr] = (WB).x; Ws[BUF][lk +17][lr] = (WB).y; \
    Ws[BUF][lk +18][lr] = (WB).z; Ws[BUF][lk +19][lr] = (WB).w; \
} while (0)

#define COMPUTE(BUF) do { \
    _Pragma("unroll") \
    for (int k = 0; k < 32; ++k) { \
        float4 av = *(const float4*)(&Xs[BUF][k][ty * 4]); \
        float4 bv = *(const float4*)(&Ws[BUF][k][tx * 4]); \
        float a_[4] = {av.x, av.y, av.z, av.w}; \
        float b_[4] = {bv.x, bv.y, bv.z, bv.w}; \
        _Pragma("unroll") \
        for (int i = 0; i < 4; ++i) \
            _Pragma("unroll") \
            for (int j = 0; j < 4; ++j) \
                acc[i][j] = fmaf(a_[i], b_[j], acc[i][j]); \
    } \
} while (0)

__global__ __launch_bounds__(256) void proj_kernel(
    const float* __restrict__ query, const float* __restrict__ memory,
    const float* __restrict__ Wq, const float* __restrict__ bq,
    const float* __restrict__ Wk, const float* __restrict__ bk,
    float* __restrict__ Eq, float* __restrict__ Ek,
    const unsigned char* __restrict__ mraw, unsigned char* __restrict__ mout) {
    const int g = blockIdx.x;
    const int t = threadIdx.x;

    if (g == 576) {   // ---- mask canonicalizer ----
        __shared__ int s_not01, s_not0f;
        const unsigned int* w = (const unsigned int*)mraw;
        if (t == 0) { s_not01 = 0; s_not0f = 0; }
        __syncthreads();
        int not01 = 0, not0f = 0;
        for (int i = t; i < 2048; i += 256) {
            unsigned int v = w[i];
            if (v != 0u && v != 1u) not01 = 1;
            if (v != 0u && v != 0x3F800000u) not0f = 1;
        }
        if (not01) atomicOr(&s_not01, 1);
        if (not0f) atomicOr(&s_not0f, 1);
        __syncthreads();
        int wordTyped = (!s_not01) || (!s_not0f);
        for (int i = t; i < B_ * ML_; i += 256) {
            unsigned char mv;
            if (wordTyped) mv = (w[i] != 0u) ? 1 : 0;
            else           mv = mraw[i] ? 1 : 0;
            mout[i] = mv;
        }
        return;
    }

    const float SC = 2.885390081777926815f;   // 2*log2(e)
    const int K = 512, N = 256;
    __shared__ float Xs[2][32][68];
    __shared__ float Ws[2][32][68];

    const int bn = (g & 7) >> 1;
    const int bm = ((g >> 3) << 1) | (g & 1);

    const float *X, *W, *bias; float* out; int mrow0;
    if (bm < 16) { X = query;  W = Wq; bias = bq; out = Eq; mrow0 = bm * 64; }
    else         { X = memory; W = Wk; bias = bk; out = Ek; mrow0 = (bm - 16) * 64; }

    const int tx = t & 15, ty = t >> 4;
    const int lr = t >> 2;           // staged row 0..63
    const int lk = (t & 3) << 2;     // staged k offset {0,4,8,12}
    const float* Xrow = X + (size_t)(mrow0 + lr) * K + lk;
    const float* Wrow = W + (size_t)(bn * 64 + lr) * K + lk;

    // slot0/slot1: named prefetch registers (compile-time only — no spill)
    float4 x0a = *(const float4*)(Xrow);      float4 x0b = *(const float4*)(Xrow + 16);
    float4 w0a = *(const float4*)(Wrow);      float4 w0b = *(const float4*)(Wrow + 16);
    float4 x1a = *(const float4*)(Xrow + 32); float4 x1b = *(const float4*)(Xrow + 48);
    float4 w1a = *(const float4*)(Wrow + 32); float4 w1b = *(const float4*)(Wrow + 48);

    STAGE(0, x0a, x0b, w0a, w0b);   // tile 0 -> buf0
    __syncthreads();

    float acc[4][4] = {};
    for (int kt = 0; kt < 16; kt += 2) {
        // ---- even phase: tile kt from buf0 ----
        if (kt + 2 < 16) {
            const float* xp = Xrow + (kt + 2) * 32;
            const float* wp = Wrow + (kt + 2) * 32;
            x0a = *(const float4*)(xp);      x0b = *(const float4*)(xp + 16);
            w0a = *(const float4*)(wp);      w0b = *(const float4*)(wp + 16);
        }
        COMPUTE(0);
        STAGE(1, x1a, x1b, w1a, w1b);       // tile kt+1 -> buf1
        __syncthreads();
        // ---- odd phase: tile kt+1 from buf1 ----
        if (kt + 3 < 16) {
            const float* xp = Xrow + (kt + 3) * 32;
            const float* wp = Wrow + (kt + 3) * 32;
            x1a = *(const float4*)(xp);      x1b = *(const float4*)(xp + 16);
            w1a = *(const float4*)(wp);      w1b = *(const float4*)(wp + 16);
        }
        COMPUTE(1);
        if (kt + 2 < 16) {
            STAGE(0, x0a, x0b, w0a, w0b);   // tile kt+2 -> buf0
            __syncthreads();
        }
    }

    float4 bv = *(const float4*)(bias + bn * 64 + tx * 4);
    float bvec[4] = {bv.x, bv.y, bv.z, bv.w};
#pragma unroll
    for (int i = 0; i < 4; ++i) {
        int m = mrow0 + ty * 4 + i;
        float4 o;
        o.x = __builtin_amdgcn_exp2f(SC * (acc[i][0] + bvec[0]));
        o.y = __builtin_amdgcn_exp2f(SC * (acc[i][1] + bvec[1]));
        o.z = __builtin_amdgcn_exp2f(SC * (acc[i][2] + bvec[2]));
        o.w = __builtin_amdgcn_exp2f(SC * (acc[i][3] + bvec[3]));
        *(float4*)(out + (size_t)m * N + bn * 64 + tx * 4) = o;
    }
}

// ---------------------------------------------------------------------------
// Logits v3 (unchanged from R5 — verified, absmax 2.4e-4):
//   sr[q][m]   = sum_h wl[h] / (Eq[q][h]*Ek[m][h] + 1)
//   u[q][m]    = mask[m] ? 0 : exp2(-2*log2e * sr)
//   psum[row][mt] = partial row-sum of u over this block's 128-m strip.
// ---------------------------------------------------------------------------
__global__ __launch_bounds__(256) void logits_kernel(
    const float* __restrict__ Eq, const float* __restrict__ Ek,
    const float* __restrict__ wl, const unsigned char* __restrict__ mcan,
    float* __restrict__ wout, float* __restrict__ psum) {
    const int bid = blockIdx.x;
    const int b  = bid & 7;
    const int r2 = bid >> 3;
    const int mt = r2 & 7;      // m tile of 128
    const int qt = r2 >> 3;     // q octet
    const int tid = threadIdx.x;
    const int m  = tid & 127;
    const int qh = tid >> 7;    // 0/1: which 4 q's

    __shared__ float eqs[2048];        // [j][h], j<8
    __shared__ float wls[256];
    __shared__ float kq[2][4][128][4]; // double-buffered 16-h chunk
    __shared__ float sred[4][4];       // [wave][j2]

    const float* qpb = Eq + ((size_t)(b * QL_ + qt * 8)) * H_;
    const float* kpb = Ek + ((size_t)(b * ML_ + mt * 128)) * H_;

    // one-time stage: Eq tile + wl
    *(float4*)(&eqs[tid * 4])        = *(const float4*)(qpb + tid * 4);
    *(float4*)(&eqs[1024 + tid * 4]) = *(const float4*)(qpb + 1024 + tid * 4);
    if (tid < 64) *(float4*)(&wls[tid * 4]) = *(const float4*)(wl + tid * 4);

    const float* kst = kpb + (size_t)m * H_ + 8 * qh;  // lane stages row m, 8 h
    float4 a0 = *(const float4*)(kst);
    float4 a1 = *(const float4*)(kst + 4);
    *(float4*)(&kq[0][2 * qh + 0][m][0]) = a0;
    *(float4*)(&kq[0][2 * qh + 1][m][0]) = a1;
    __syncthreads();

    float acc[4] = {0.f, 0.f, 0.f, 0.f};

    for (int c = 0; c < 16; ++c) {
        if (c < 15) {
            a0 = *(const float4*)(kst + (c + 1) * 16);
            a1 = *(const float4*)(kst + (c + 1) * 16 + 4);
        }
        const int buf = c & 1;
        const int h0 = c * 16;
#pragma unroll
        for (int quad = 0; quad < 4; ++quad) {
            float4 k4 = *(const float4*)(&kq[buf][quad][m][0]);
            float4 w4 = *(const float4*)(&wls[h0 + quad * 4]);
#pragma unroll
            for (int j2 = 0; j2 < 4; ++j2) {
                float4 q4 = *(const float4*)(&eqs[(qh * 4 + j2) * 256 + h0 + quad * 4]);
                float p0 = fmaf(k4.x, q4.x, 1.0f);
                float p1 = fmaf(k4.y, q4.y, 1.0f);
                float p2 = fmaf(k4.z, q4.z, 1.0f);
                float p3 = fmaf(k4.w, q4.w, 1.0f);
                float p01 = p0 * p1, p23 = p2 * p3;
                float n01 = fmaf(w4.y, p0, w4.x * p1);
                float n23 = fmaf(w4.w, p2, w4.z * p3);
                float Nm  = fmaf(n23, p01, n01 * p23);
                float P   = p01 * p23;
                acc[j2] = fmaf(Nm, __builtin_amdgcn_rcpf(P), acc[j2]);
            }
        }
        if (c < 15) {
            *(float4*)(&kq[buf ^ 1][2 * qh + 0][m][0]) = a0;
            *(float4*)(&kq[buf ^ 1][2 * qh + 1][m][0]) = a1;
            __syncthreads();
        }
    }

    // u = exp2(-2*log2e * sr), masked -> 0 (mask depends only on m)
    const float N2L = -2.885390081777926815f;   // -2*log2(e)
    const int mk = mcan[b * ML_ + mt * 128 + m];
    float u[4];
#pragma unroll
    for (int j2 = 0; j2 < 4; ++j2) {
        u[j2] = mk ? 0.f : __builtin_amdgcn_exp2f(N2L * acc[j2]);
        wout[((size_t)(b * QL_ + qt * 8 + qh * 4 + j2)) * ML_ + mt * 128 + m] = u[j2];
    }

    // partial row sums over this 128-m strip (deterministic, no atomics)
    float r[4] = {u[0], u[1], u[2], u[3]};
#pragma unroll
    for (int off = 32; off >= 1; off >>= 1) {
#pragma unroll
        for (int j2 = 0; j2 < 4; ++j2)
            r[j2] += __shfl_xor(r[j2], off);
    }
    if ((tid & 63) == 0) {
#pragma unroll
        for (int j2 = 0; j2 < 4; ++j2)
            sred[tid >> 6][j2] = r[j2];
    }
    __syncthreads();
    if (tid < 8) {
        const int q = tid;
        float v = sred[(q >> 2) * 2][q & 3] + sred[(q >> 2) * 2 + 1][q & 3];
        psum[((size_t)(b * QL_ + qt * 8 + q)) * 8 + mt] = v;
    }
}

// ---------------------------------------------------------------------------
// attns[b] = (u[b] @ M[b]) * inv_rowsum. LDS-tiled GEMM, epilogue-normalized.
// ---------------------------------------------------------------------------
__global__ __launch_bounds__(256) void attn_out_kernel(
    const float* __restrict__ wgt, const float* __restrict__ mem,
    const float* __restrict__ psum, float* __restrict__ out) {
    const int bid = blockIdx.x;
    const int b  = bid & 7;
    const int j2 = bid >> 3;
    const int mt = j2 & 3;
    const int nt = j2 >> 2;
    const int t = threadIdx.x;
    __shared__ float As[32][34];
    __shared__ float Bs[32][64];

    const int ar = t >> 3, ac = (t & 7) << 2;
    const int br = t >> 4, bc = (t & 15) << 2;
    const float* Ap = wgt + ((size_t)(b * QL_ + mt * 32 + ar)) * ML_ + ac;
    const float* Bp = mem + ((size_t)(b * ML_ + br)) * KS_ + nt * 64 + bc;

    const int tx = t & 15, ty = t >> 4;
    float acc0[4] = {0.f, 0.f, 0.f, 0.f};
    float acc1[4] = {0.f, 0.f, 0.f, 0.f};

    float4 apre = *(const float4*)(Ap);
    float4 bpre0 = *(const float4*)(Bp);
    float4 bpre1 = *(const float4*)(Bp + (size_t)16 * KS_);

    for (int k0 = 0; k0 < ML_; k0 += 32) {
        __syncthreads();
        As[ac + 0][ar] = apre.x; As[ac + 1][ar] = apre.y;
        As[ac + 2][ar] = apre.z; As[ac + 3][ar] = apre.w;
        *(float4*)(&Bs[br][bc])      = bpre0;
        *(float4*)(&Bs[br + 16][bc]) = bpre1;
        __syncthreads();
        if (k0 + 32 < ML_) {
            apre  = *(const float4*)(Ap + k0 + 32);
            bpre0 = *(const float4*)(Bp + (size_t)(k0 + 32) * KS_);
            bpre1 = *(const float4*)(Bp + (size_t)(k0 + 48) * KS_);
        }
#pragma unroll
        for (int kk = 0; kk < 32; ++kk) {
            float2 a2 = *(const float2*)(&As[kk][ty * 2]);
            float4 b4 = *(const float4*)(&Bs[kk][tx * 4]);
            acc0[0] = fmaf(a2.x, b4.x, acc0[0]);
            acc0[1] = fmaf(a2.x, b4.y, acc0[1]);
            acc0[2] = fmaf(a2.x, b4.z, acc0[2]);
            acc0[3] = fmaf(a2.x, b4.w, acc0[3]);
            acc1[0] = fmaf(a2.y, b4.x, acc1[0]);
            acc1[1] = fmaf(a2.y, b4.y, acc1[1]);
            acc1[2] = fmaf(a2.y, b4.z, acc1[2]);
            acc1[3] = fmaf(a2.y, b4.w, acc1[3]);
        }
    }
    // epilogue: normalize by row sums (8 partials per row, block-uniform rows)
    const float* ps = psum + ((size_t)(b * QL_ + mt * 32 + ty * 2)) * 8;
    float rs0 = 0.f, rs1 = 0.f;
#pragma unroll
    for (int i = 0; i < 8; ++i) { rs0 += ps[i]; rs1 += ps[8 + i]; }
    float inv0 = __builtin_amdgcn_rcpf(rs0);
    float inv1 = __builtin_amdgcn_rcpf(rs1);

    size_t orow = ((size_t)(b * QL_ + mt * 32 + ty * 2)) * KS_ + nt * 64 + tx * 4;
    *(float4*)(out + orow)       = make_float4(acc0[0] * inv0, acc0[1] * inv0,
                                               acc0[2] * inv0, acc0[3] * inv0);
    *(float4*)(out + orow + KS_) = make_float4(acc1[0] * inv1, acc1[1] * inv1,
                                               acc1[2] * inv1, acc1[3] * inv1);
}

// ---------------------------------------------------------------------------
// Normalize the weights output in place (runs AFTER attn_out consumed u).
// ---------------------------------------------------------------------------
__global__ __launch_bounds__(256) void scale_weights(
    float* __restrict__ wout, const float* __restrict__ psum) {
    const int row = blockIdx.x;          // b*QL + q
    const int tid = threadIdx.x;
    const float* ps = psum + (size_t)row * 8;
    float rs = ((ps[0] + ps[1]) + (ps[2] + ps[3])) +
               ((ps[4] + ps[5]) + (ps[6] + ps[7]));
    float inv = __builtin_amdgcn_rcpf(rs);
    float4* p = (float4*)(wout + (size_t)row * ML_ + tid * 4);
    float4 v = *p;
    *p = make_float4(v.x * inv, v.y * inv, v.z * inv, v.w * inv);
}

extern "C" void kernel_launch(void* const* d_in, const int* in_sizes, int n_in,
                              void* d_out, int out_size, void* d_ws, size_t ws_size,
                              hipStream_t stream) {
    const float* query  = (const float*)d_in[0];
    const float* memory = (const float*)d_in[1];
    const unsigned char* mask = (const unsigned char*)d_in[2];
    const float* Wq = (const float*)d_in[3];
    const float* bq = (const float*)d_in[4];
    const float* Wk = (const float*)d_in[5];
    const float* bk = (const float*)d_in[6];
    const float* wl = (const float*)d_in[7];
    // d_in[8] (bl) cancels under softmax shift-invariance; not read.

    float* ws = (float*)d_ws;
    float* Eq = ws + QP_OFF;
    float* Ek = ws + KP_OFF;
    unsigned char* mcan = (unsigned char*)(ws + MASK_OFF);
    float* psum = ws + PSUM_OFF;

    float* attns = (float*)d_out;                      // [B][QL][KS]
    float* wout  = (float*)d_out + B_ * QL_ * KS_;     // [B][QL][ML]: u, then weights

    proj_kernel<<<dim3(577), dim3(256), 0, stream>>>(query, memory, Wq, bq, Wk, bk,
                                                     Eq, Ek, mask, mcan);
    logits_kernel<<<dim3(1024), dim3(256), 0, stream>>>(Eq, Ek, wl, mcan, wout, psum);
    attn_out_kernel<<<dim3(256), dim3(256), 0, stream>>>(wout, memory, psum, attns);
    scale_weights<<<dim3(B_ * QL_), dim3(256), 0, stream>>>(wout, psum);
}

// Round 7
// 226.997 us; speedup vs baseline: 1.0622x; 1.0158x over previous
//
#include <hip/hip_runtime.h>

#define B_  8
#define QL_ 128
#define ML_ 1024
#define KS_ 512
#define H_  256

// ws layout (floats):
//   Eq = exp2(2log2e * qproj): [B][QL][H]  @ 0        (262144 floats)
//   Ek = exp2(2log2e * kproj): [B][ML][H]  @ 262144   (2097152 floats)
//   mask canonical uint8 [B*ML]            @ 2359296  (8192 bytes = 2048 floats)
//   psum [B*QL][8] partial row sums        @ 2361344  (8192 floats)
#define QP_OFF 0
#define KP_OFF 262144
#define MASK_OFF 2359296
#define PSUM_OFF 2361344

// ---------------------------------------------------------------------------
// Fused projection kernel, v5: BK=32, double-buffered LDS, ONE barrier per
// k-tile (16 total vs R3's 64), 1-deep prefetch with a SINGLE named register
// set (16 VGPRs — R6's 164-VGPR occupancy collapse came from 2-deep/unrolled
// regs; R5's 144 MB scratch spill from dynamically-indexed register arrays.
// Dynamic indexing is ONLY on LDS buffers here, which is plain address math).
// Flat grid of 577 blocks: g 0..575 GEMM tiles (M = 1024 query + 8192 memory
// rows), g 576 mask canonicalizer.
// out[m][n] = exp2( SC * (sum_k X[m][k]*W[n][k] + bias[n]) ), K=512, N=256.
// ---------------------------------------------------------------------------
__global__ __launch_bounds__(256) void proj_kernel(
    const float* __restrict__ query, const float* __restrict__ memory,
    const float* __restrict__ Wq, const float* __restrict__ bq,
    const float* __restrict__ Wk, const float* __restrict__ bk,
    float* __restrict__ Eq, float* __restrict__ Ek,
    const unsigned char* __restrict__ mraw, unsigned char* __restrict__ mout) {
    const int g = blockIdx.x;
    const int t = threadIdx.x;

    if (g == 576) {   // ---- mask canonicalizer ----
        __shared__ int s_not01, s_not0f;
        const unsigned int* w = (const unsigned int*)mraw;
        if (t == 0) { s_not01 = 0; s_not0f = 0; }
        __syncthreads();
        int not01 = 0, not0f = 0;
        for (int i = t; i < 2048; i += 256) {
            unsigned int v = w[i];
            if (v != 0u && v != 1u) not01 = 1;
            if (v != 0u && v != 0x3F800000u) not0f = 1;
        }
        if (not01) atomicOr(&s_not01, 1);
        if (not0f) atomicOr(&s_not0f, 1);
        __syncthreads();
        int wordTyped = (!s_not01) || (!s_not0f);
        for (int i = t; i < B_ * ML_; i += 256) {
            unsigned char mv;
            if (wordTyped) mv = (w[i] != 0u) ? 1 : 0;
            else           mv = mraw[i] ? 1 : 0;
            mout[i] = mv;
        }
        return;
    }

    const float SC = 2.885390081777926815f;   // 2*log2(e)
    const int K = 512, N = 256;
    __shared__ float Xs[2][32][68];
    __shared__ float Ws[2][32][68];

    const int bn = (g & 7) >> 1;
    const int bm = ((g >> 3) << 1) | (g & 1);

    const float *X, *W, *bias; float* out; int mrow0;
    if (bm < 16) { X = query;  W = Wq; bias = bq; out = Eq; mrow0 = bm * 64; }
    else         { X = memory; W = Wk; bias = bk; out = Ek; mrow0 = (bm - 16) * 64; }

    const int tx = t & 15, ty = t >> 4;
    const int lr = t >> 2;           // staged row 0..63
    const int lk = (t & 3) << 2;     // staged k offset {0,4,8,12}
    const float* Xrow = X + (size_t)(mrow0 + lr) * K + lk;
    const float* Wrow = W + (size_t)(bn * 64 + lr) * K + lk;

    // single prefetch register set (4 float4 = 16 VGPRs, never indexed)
    float4 xa = *(const float4*)(Xrow);      float4 xb = *(const float4*)(Xrow + 16);
    float4 wa = *(const float4*)(Wrow);      float4 wb = *(const float4*)(Wrow + 16);

    // stage tile 0 -> buf 0
    Xs[0][lk + 0][lr] = xa.x; Xs[0][lk + 1][lr] = xa.y;
    Xs[0][lk + 2][lr] = xa.z; Xs[0][lk + 3][lr] = xa.w;
    Xs[0][lk +16][lr] = xb.x; Xs[0][lk +17][lr] = xb.y;
    Xs[0][lk +18][lr] = xb.z; Xs[0][lk +19][lr] = xb.w;
    Ws[0][lk + 0][lr] = wa.x; Ws[0][lk + 1][lr] = wa.y;
    Ws[0][lk + 2][lr] = wa.z; Ws[0][lk + 3][lr] = wa.w;
    Ws[0][lk +16][lr] = wb.x; Ws[0][lk +17][lr] = wb.y;
    Ws[0][lk +18][lr] = wb.z; Ws[0][lk +19][lr] = wb.w;
    __syncthreads();

    float acc[4][4] = {};
    for (int kt = 0; kt < 16; ++kt) {
        const int cur = kt & 1;        // LDS buffer index only (address math)
        // issue loads for tile kt+1 (consumed after compute below)
        if (kt + 1 < 16) {
            const float* xp = Xrow + (kt + 1) * 32;
            const float* wp = Wrow + (kt + 1) * 32;
            xa = *(const float4*)(xp);      xb = *(const float4*)(xp + 16);
            wa = *(const float4*)(wp);      wb = *(const float4*)(wp + 16);
        }
        // compute tile kt from buf[cur] (~1000 cy; hides the loads above)
#pragma unroll
        for (int k = 0; k < 32; ++k) {
            float4 av = *(const float4*)(&Xs[cur][k][ty * 4]);
            float4 bv = *(const float4*)(&Ws[cur][k][tx * 4]);
            float a_[4] = {av.x, av.y, av.z, av.w};
            float b_[4] = {bv.x, bv.y, bv.z, bv.w};
#pragma unroll
            for (int i = 0; i < 4; ++i)
#pragma unroll
                for (int j = 0; j < 4; ++j)
                    acc[i][j] = fmaf(a_[i], b_[j], acc[i][j]);
        }
        // stage tile kt+1 -> other buffer; ONE barrier per tile
        if (kt + 1 < 16) {
            const int nxt = cur ^ 1;
            Xs[nxt][lk + 0][lr] = xa.x; Xs[nxt][lk + 1][lr] = xa.y;
            Xs[nxt][lk + 2][lr] = xa.z; Xs[nxt][lk + 3][lr] = xa.w;
            Xs[nxt][lk +16][lr] = xb.x; Xs[nxt][lk +17][lr] = xb.y;
            Xs[nxt][lk +18][lr] = xb.z; Xs[nxt][lk +19][lr] = xb.w;
            Ws[nxt][lk + 0][lr] = wa.x; Ws[nxt][lk + 1][lr] = wa.y;
            Ws[nxt][lk + 2][lr] = wa.z; Ws[nxt][lk + 3][lr] = wa.w;
            Ws[nxt][lk +16][lr] = wb.x; Ws[nxt][lk +17][lr] = wb.y;
            Ws[nxt][lk +18][lr] = wb.z; Ws[nxt][lk +19][lr] = wb.w;
            __syncthreads();
        }
    }

    float4 bv = *(const float4*)(bias + bn * 64 + tx * 4);
    float bvec[4] = {bv.x, bv.y, bv.z, bv.w};
#pragma unroll
    for (int i = 0; i < 4; ++i) {
        int m = mrow0 + ty * 4 + i;
        float4 o;
        o.x = __builtin_amdgcn_exp2f(SC * (acc[i][0] + bvec[0]));
        o.y = __builtin_amdgcn_exp2f(SC * (acc[i][1] + bvec[1]));
        o.z = __builtin_amdgcn_exp2f(SC * (acc[i][2] + bvec[2]));
        o.w = __builtin_amdgcn_exp2f(SC * (acc[i][3] + bvec[3]));
        *(float4*)(out + (size_t)m * N + bn * 64 + tx * 4) = o;
    }
}

// ---------------------------------------------------------------------------
// Logits v3 (unchanged — verified, absmax 2.4e-4):
//   sr[q][m]   = sum_h wl[h] / (Eq[q][h]*Ek[m][h] + 1)
//   u[q][m]    = mask[m] ? 0 : exp2(-2*log2e * sr)
//   psum[row][mt] = partial row-sum of u over this block's 128-m strip.
// ---------------------------------------------------------------------------
__global__ __launch_bounds__(256) void logits_kernel(
    const float* __restrict__ Eq, const float* __restrict__ Ek,
    const float* __restrict__ wl, const unsigned char* __restrict__ mcan,
    float* __restrict__ wout, float* __restrict__ psum) {
    const int bid = blockIdx.x;
    const int b  = bid & 7;
    const int r2 = bid >> 3;
    const int mt = r2 & 7;      // m tile of 128
    const int qt = r2 >> 3;     // q octet
    const int tid = threadIdx.x;
    const int m  = tid & 127;
    const int qh = tid >> 7;    // 0/1: which 4 q's

    __shared__ float eqs[2048];        // [j][h], j<8
    __shared__ float wls[256];
    __shared__ float kq[2][4][128][4]; // double-buffered 16-h chunk
    __shared__ float sred[4][4];       // [wave][j2]

    const float* qpb = Eq + ((size_t)(b * QL_ + qt * 8)) * H_;
    const float* kpb = Ek + ((size_t)(b * ML_ + mt * 128)) * H_;

    // one-time stage: Eq tile + wl
    *(float4*)(&eqs[tid * 4])        = *(const float4*)(qpb + tid * 4);
    *(float4*)(&eqs[1024 + tid * 4]) = *(const float4*)(qpb + 1024 + tid * 4);
    if (tid < 64) *(float4*)(&wls[tid * 4]) = *(const float4*)(wl + tid * 4);

    const float* kst = kpb + (size_t)m * H_ + 8 * qh;  // lane stages row m, 8 h
    float4 a0 = *(const float4*)(kst);
    float4 a1 = *(const float4*)(kst + 4);
    *(float4*)(&kq[0][2 * qh + 0][m][0]) = a0;
    *(float4*)(&kq[0][2 * qh + 1][m][0]) = a1;
    __syncthreads();

    float acc[4] = {0.f, 0.f, 0.f, 0.f};

    for (int c = 0; c < 16; ++c) {
        if (c < 15) {
            a0 = *(const float4*)(kst + (c + 1) * 16);
            a1 = *(const float4*)(kst + (c + 1) * 16 + 4);
        }
        const int buf = c & 1;
        const int h0 = c * 16;
#pragma unroll
        for (int quad = 0; quad < 4; ++quad) {
            float4 k4 = *(const float4*)(&kq[buf][quad][m][0]);
            float4 w4 = *(const float4*)(&wls[h0 + quad * 4]);
#pragma unroll
            for (int j2 = 0; j2 < 4; ++j2) {
                float4 q4 = *(const float4*)(&eqs[(qh * 4 + j2) * 256 + h0 + quad * 4]);
                float p0 = fmaf(k4.x, q4.x, 1.0f);
                float p1 = fmaf(k4.y, q4.y, 1.0f);
                float p2 = fmaf(k4.z, q4.z, 1.0f);
                float p3 = fmaf(k4.w, q4.w, 1.0f);
                float p01 = p0 * p1, p23 = p2 * p3;
                float n01 = fmaf(w4.y, p0, w4.x * p1);
                float n23 = fmaf(w4.w, p2, w4.z * p3);
                float Nm  = fmaf(n23, p01, n01 * p23);
                float P   = p01 * p23;
                acc[j2] = fmaf(Nm, __builtin_amdgcn_rcpf(P), acc[j2]);
            }
        }
        if (c < 15) {
            *(float4*)(&kq[buf ^ 1][2 * qh + 0][m][0]) = a0;
            *(float4*)(&kq[buf ^ 1][2 * qh + 1][m][0]) = a1;
            __syncthreads();
        }
    }

    // u = exp2(-2*log2e * sr), masked -> 0 (mask depends only on m)
    const float N2L = -2.885390081777926815f;   // -2*log2(e)
    const int mk = mcan[b * ML_ + mt * 128 + m];
    float u[4];
#pragma unroll
    for (int j2 = 0; j2 < 4; ++j2) {
        u[j2] = mk ? 0.f : __builtin_amdgcn_exp2f(N2L * acc[j2]);
        wout[((size_t)(b * QL_ + qt * 8 + qh * 4 + j2)) * ML_ + mt * 128 + m] = u[j2];
    }

    // partial row sums over this 128-m strip (deterministic, no atomics)
    float r[4] = {u[0], u[1], u[2], u[3]};
#pragma unroll
    for (int off = 32; off >= 1; off >>= 1) {
#pragma unroll
        for (int j2 = 0; j2 < 4; ++j2)
            r[j2] += __shfl_xor(r[j2], off);
    }
    if ((tid & 63) == 0) {
#pragma unroll
        for (int j2 = 0; j2 < 4; ++j2)
            sred[tid >> 6][j2] = r[j2];
    }
    __syncthreads();
    if (tid < 8) {
        const int q = tid;
        float v = sred[(q >> 2) * 2][q & 3] + sred[(q >> 2) * 2 + 1][q & 3];
        psum[((size_t)(b * QL_ + qt * 8 + q)) * 8 + mt] = v;
    }
}

// ---------------------------------------------------------------------------
// attns[b] = (u[b] @ M[b]) * inv_rowsum. LDS-tiled GEMM, epilogue-normalized.
// ---------------------------------------------------------------------------
__global__ __launch_bounds__(256) void attn_out_kernel(
    const float* __restrict__ wgt, const float* __restrict__ mem,
    const float* __restrict__ psum, float* __restrict__ out) {
    const int bid = blockIdx.x;
    const int b  = bid & 7;
    const int j2 = bid >> 3;
    const int mt = j2 & 3;
    const int nt = j2 >> 2;
    const int t = threadIdx.x;
    __shared__ float As[32][34];
    __shared__ float Bs[32][64];

    const int ar = t >> 3, ac = (t & 7) << 2;
    const int br = t >> 4, bc = (t & 15) << 2;
    const float* Ap = wgt + ((size_t)(b * QL_ + mt * 32 + ar)) * ML_ + ac;
    const float* Bp = mem + ((size_t)(b * ML_ + br)) * KS_ + nt * 64 + bc;

    const int tx = t & 15, ty = t >> 4;
    float acc0[4] = {0.f, 0.f, 0.f, 0.f};
    float acc1[4] = {0.f, 0.f, 0.f, 0.f};

    float4 apre = *(const float4*)(Ap);
    float4 bpre0 = *(const float4*)(Bp);
    float4 bpre1 = *(const float4*)(Bp + (size_t)16 * KS_);

    for (int k0 = 0; k0 < ML_; k0 += 32) {
        __syncthreads();
        As[ac + 0][ar] = apre.x; As[ac + 1][ar] = apre.y;
        As[ac + 2][ar] = apre.z; As[ac + 3][ar] = apre.w;
        *(float4*)(&Bs[br][bc])      = bpre0;
        *(float4*)(&Bs[br + 16][bc]) = bpre1;
        __syncthreads();
        if (k0 + 32 < ML_) {
            apre  = *(const float4*)(Ap + k0 + 32);
            bpre0 = *(const float4*)(Bp + (size_t)(k0 + 32) * KS_);
            bpre1 = *(const float4*)(Bp + (size_t)(k0 + 48) * KS_);
        }
#pragma unroll
        for (int kk = 0; kk < 32; ++kk) {
            float2 a2 = *(const float2*)(&As[kk][ty * 2]);
            float4 b4 = *(const float4*)(&Bs[kk][tx * 4]);
            acc0[0] = fmaf(a2.x, b4.x, acc0[0]);
            acc0[1] = fmaf(a2.x, b4.y, acc0[1]);
            acc0[2] = fmaf(a2.x, b4.z, acc0[2]);
            acc0[3] = fmaf(a2.x, b4.w, acc0[3]);
            acc1[0] = fmaf(a2.y, b4.x, acc1[0]);
            acc1[1] = fmaf(a2.y, b4.y, acc1[1]);
            acc1[2] = fmaf(a2.y, b4.z, acc1[2]);
            acc1[3] = fmaf(a2.y, b4.w, acc1[3]);
        }
    }
    // epilogue: normalize by row sums (8 partials per row, block-uniform rows)
    const float* ps = psum + ((size_t)(b * QL_ + mt * 32 + ty * 2)) * 8;
    float rs0 = 0.f, rs1 = 0.f;
#pragma unroll
    for (int i = 0; i < 8; ++i) { rs0 += ps[i]; rs1 += ps[8 + i]; }
    float inv0 = __builtin_amdgcn_rcpf(rs0);
    float inv1 = __builtin_amdgcn_rcpf(rs1);

    size_t orow = ((size_t)(b * QL_ + mt * 32 + ty * 2)) * KS_ + nt * 64 + tx * 4;
    *(float4*)(out + orow)       = make_float4(acc0[0] * inv0, acc0[1] * inv0,
                                               acc0[2] * inv0, acc0[3] * inv0);
    *(float4*)(out + orow + KS_) = make_float4(acc1[0] * inv1, acc1[1] * inv1,
                                               acc1[2] * inv1, acc1[3] * inv1);
}

// ---------------------------------------------------------------------------
// Normalize the weights output in place (runs AFTER attn_out consumed u).
// ---------------------------------------------------------------------------
__global__ __launch_bounds__(256) void scale_weights(
    float* __restrict__ wout, const float* __restrict__ psum) {
    const int row = blockIdx.x;          // b*QL + q
    const int tid = threadIdx.x;
    const float* ps = psum + (size_t)row * 8;
    float rs = ((ps[0] + ps[1]) + (ps[2] + ps[3])) +
               ((ps[4] + ps[5]) + (ps[6] + ps[7]));
    float inv = __builtin_amdgcn_rcpf(rs);
    float4* p = (float4*)(wout + (size_t)row * ML_ + tid * 4);
    float4 v = *p;
    *p = make_float4(v.x * inv, v.y * inv, v.z * inv, v.w * inv);
}

extern "C" void kernel_launch(void* const* d_in, const int* in_sizes, int n_in,
                              void* d_out, int out_size, void* d_ws, size_t ws_size,
                              hipStream_t stream) {
    const float* query  = (const float*)d_in[0];
    const float* memory = (const float*)d_in[1];
    const unsigned char* mask = (const unsigned char*)d_in[2];
    const float* Wq = (const float*)d_in[3];
    const float* bq = (const float*)d_in[4];
    const float* Wk = (const float*)d_in[5];
    const float* bk = (const float*)d_in[6];
    const float* wl = (const float*)d_in[7];
    // d_in[8] (bl) cancels under softmax shift-invariance; not read.

    float* ws = (float*)d_ws;
    float* Eq = ws + QP_OFF;
    float* Ek = ws + KP_OFF;
    unsigned char* mcan = (unsigned char*)(ws + MASK_OFF);
    float* psum = ws + PSUM_OFF;

    float* attns = (float*)d_out;                      // [B][QL][KS]
    float* wout  = (float*)d_out + B_ * QL_ * KS_;     // [B][QL][ML]: u, then weights

    proj_kernel<<<dim3(577), dim3(256), 0, stream>>>(query, memory, Wq, bq, Wk, bk,
                                                     Eq, Ek, mask, mcan);
    logits_kernel<<<dim3(1024), dim3(256), 0, stream>>>(Eq, Ek, wl, mcan, wout, psum);
    attn_out_kernel<<<dim3(256), dim3(256), 0, stream>>>(wout, memory, psum, attns);
    scale_weights<<<dim3(B_ * QL_), dim3(256), 0, stream>>>(wout, psum);
}

// Round 8
// 214.495 us; speedup vs baseline: 1.1241x; 1.0583x over previous
//
#include <hip/hip_runtime.h>

#define B_  8
#define QL_ 128
#define ML_ 1024
#define KS_ 512
#define H_  256

// ws layout (floats):
//   Eq = exp2(2log2e * qproj): [B][QL][H]  @ 0        (262144 floats)
//   Ek = exp2(2log2e * kproj): [B][ML][H]  @ 262144   (2097152 floats)
//   mask canonical uint8 [B*ML]            @ 2359296  (8192 bytes = 2048 floats)
//   psum [B*QL][8] partial row sums        @ 2361344  (8192 floats)
#define QP_OFF 0
#define KP_OFF 262144
#define MASK_OFF 2359296
#define PSUM_OFF 2361344

// ---------------------------------------------------------------------------
// Projection kernel v6: WAVE-PER-BLOCK. 64 threads, 32x32 tile, 4x4 microtile,
// BK=16 double-buffered LDS. Rationale (R5-R7 post-mortems): 256-thread
// barrier-coupled GEMM blocks stall at 8-15% occupancy regardless of prefetch
// depth; single-wave blocks have near-free barriers and the 2304-block grid
// = exactly 9 independent waves/CU (imbalance 1.0) -> latency hidden by TLP.
// Row pad = 36 floats (144 B = 16B-aligned rows for ds_read_b128).
// Grid: g 0..2303 tiles (bn = g&7, bmi = g>>3; rows 0..1023 query, rest mem);
//       g 2304 mask canonicalizer.
// out[m][n] = exp2( SC * (sum_k X[m][k]*W[n][k] + bias[n]) ), K=512, N=256.
// ---------------------------------------------------------------------------
__global__ __launch_bounds__(64) void proj_kernel(
    const float* __restrict__ query, const float* __restrict__ memory,
    const float* __restrict__ Wq, const float* __restrict__ bq,
    const float* __restrict__ Wk, const float* __restrict__ bk,
    float* __restrict__ Eq, float* __restrict__ Ek,
    const unsigned char* __restrict__ mraw, unsigned char* __restrict__ mout) {
    const int g = blockIdx.x;
    const int t = threadIdx.x;

    if (g == 2304) {   // ---- mask canonicalizer (one wave) ----
        const unsigned int* w = (const unsigned int*)mraw;
        int not01 = 0, not0f = 0;
        for (int i = t; i < 2048; i += 64) {
            unsigned int v = w[i];
            if (v != 0u && v != 1u) not01 = 1;
            if (v != 0u && v != 0x3F800000u) not0f = 1;
        }
        not01 = __any(not01);
        not0f = __any(not0f);
        int wordTyped = (!not01) || (!not0f);
        for (int i = t; i < B_ * ML_; i += 64) {
            unsigned char mv;
            if (wordTyped) mv = (w[i] != 0u) ? 1 : 0;
            else           mv = mraw[i] ? 1 : 0;
            mout[i] = mv;
        }
        return;
    }

    const float SC = 2.885390081777926815f;   // 2*log2(e)
    const int K = 512, N = 256;
    __shared__ float As[2][16][36];   // [buf][k][m], 144 B rows (16B-aligned)
    __shared__ float Bs[2][16][36];   // [buf][k][n]

    const int bn  = g & 7;            // n-tile of 32
    const int bmi = g >> 3;           // 0..287 combined m-tile
    const int n0  = bn * 32;

    const float *X, *W, *bias; float* out; int mrow0;
    if (bmi < 32) { X = query;  W = Wq; bias = bq; out = Eq; mrow0 = bmi * 32; }
    else          { X = memory; W = Wk; bias = bk; out = Ek; mrow0 = (bmi - 32) * 32; }

    const int tx = t & 7, ty = t >> 3;     // output microtile coords
    const int lr  = t >> 1;                // staging row 0..31
    const int lko = (t & 1) * 8;           // staging k-offset 0/8
    const float* Xrow = X + (size_t)(mrow0 + lr) * K + lko;
    const float* Wrow = W + (size_t)(n0 + lr) * K + lko;

    // single prefetch register set (4 float4)
    float4 xa = *(const float4*)(Xrow);     float4 xb = *(const float4*)(Xrow + 4);
    float4 wa = *(const float4*)(Wrow);     float4 wb = *(const float4*)(Wrow + 4);

    // stage chunk 0 -> buf 0 (transposed [k][row]; 2-way bank alias = free)
    As[0][lko + 0][lr] = xa.x; As[0][lko + 1][lr] = xa.y;
    As[0][lko + 2][lr] = xa.z; As[0][lko + 3][lr] = xa.w;
    As[0][lko + 4][lr] = xb.x; As[0][lko + 5][lr] = xb.y;
    As[0][lko + 6][lr] = xb.z; As[0][lko + 7][lr] = xb.w;
    Bs[0][lko + 0][lr] = wa.x; Bs[0][lko + 1][lr] = wa.y;
    Bs[0][lko + 2][lr] = wa.z; Bs[0][lko + 3][lr] = wa.w;
    Bs[0][lko + 4][lr] = wb.x; Bs[0][lko + 5][lr] = wb.y;
    Bs[0][lko + 6][lr] = wb.z; Bs[0][lko + 7][lr] = wb.w;
    __syncthreads();   // single-wave barrier: cheap

    float acc[4][4] = {};
    for (int c = 0; c < 32; ++c) {
        const int cur = c & 1;             // LDS buffer index (address math)
        if (c + 1 < 32) {
            const float* xp = Xrow + (c + 1) * 16;
            const float* wp = Wrow + (c + 1) * 16;
            xa = *(const float4*)(xp);     xb = *(const float4*)(xp + 4);
            wa = *(const float4*)(wp);     wb = *(const float4*)(wp + 4);
        }
#pragma unroll
        for (int k = 0; k < 16; ++k) {
            float4 av = *(const float4*)(&As[cur][k][ty * 4]);
            float4 bv = *(const float4*)(&Bs[cur][k][tx * 4]);
            float a_[4] = {av.x, av.y, av.z, av.w};
            float b_[4] = {bv.x, bv.y, bv.z, bv.w};
#pragma unroll
            for (int i = 0; i < 4; ++i)
#pragma unroll
                for (int j = 0; j < 4; ++j)
                    acc[i][j] = fmaf(a_[i], b_[j], acc[i][j]);
        }
        if (c + 1 < 32) {
            const int nxt = cur ^ 1;
            As[nxt][lko + 0][lr] = xa.x; As[nxt][lko + 1][lr] = xa.y;
            As[nxt][lko + 2][lr] = xa.z; As[nxt][lko + 3][lr] = xa.w;
            As[nxt][lko + 4][lr] = xb.x; As[nxt][lko + 5][lr] = xb.y;
            As[nxt][lko + 6][lr] = xb.z; As[nxt][lko + 7][lr] = xb.w;
            Bs[nxt][lko + 0][lr] = wa.x; Bs[nxt][lko + 1][lr] = wa.y;
            Bs[nxt][lko + 2][lr] = wa.z; Bs[nxt][lko + 3][lr] = wa.w;
            Bs[nxt][lko + 4][lr] = wb.x; Bs[nxt][lko + 5][lr] = wb.y;
            Bs[nxt][lko + 6][lr] = wb.z; Bs[nxt][lko + 7][lr] = wb.w;
            __syncthreads();
        }
    }

    float4 bv = *(const float4*)(bias + n0 + tx * 4);
    float bvec[4] = {bv.x, bv.y, bv.z, bv.w};
#pragma unroll
    for (int i = 0; i < 4; ++i) {
        int m = mrow0 + ty * 4 + i;
        float4 o;
        o.x = __builtin_amdgcn_exp2f(SC * (acc[i][0] + bvec[0]));
        o.y = __builtin_amdgcn_exp2f(SC * (acc[i][1] + bvec[1]));
        o.z = __builtin_amdgcn_exp2f(SC * (acc[i][2] + bvec[2]));
        o.w = __builtin_amdgcn_exp2f(SC * (acc[i][3] + bvec[3]));
        *(float4*)(out + (size_t)m * N + n0 + tx * 4) = o;
    }
}

// ---------------------------------------------------------------------------
// Logits v3 (unchanged — verified, absmax 2.4e-4):
//   sr[q][m]   = sum_h wl[h] / (Eq[q][h]*Ek[m][h] + 1)
//   u[q][m]    = mask[m] ? 0 : exp2(-2*log2e * sr)
//   psum[row][mt] = partial row-sum of u over this block's 128-m strip.
// ---------------------------------------------------------------------------
__global__ __launch_bounds__(256) void logits_kernel(
    const float* __restrict__ Eq, const float* __restrict__ Ek,
    const float* __restrict__ wl, const unsigned char* __restrict__ mcan,
    float* __restrict__ wout, float* __restrict__ psum) {
    const int bid = blockIdx.x;
    const int b  = bid & 7;
    const int r2 = bid >> 3;
    const int mt = r2 & 7;      // m tile of 128
    const int qt = r2 >> 3;     // q octet
    const int tid = threadIdx.x;
    const int m  = tid & 127;
    const int qh = tid >> 7;    // 0/1: which 4 q's

    __shared__ float eqs[2048];        // [j][h], j<8
    __shared__ float wls[256];
    __shared__ float kq[2][4][128][4]; // double-buffered 16-h chunk
    __shared__ float sred[4][4];       // [wave][j2]

    const float* qpb = Eq + ((size_t)(b * QL_ + qt * 8)) * H_;
    const float* kpb = Ek + ((size_t)(b * ML_ + mt * 128)) * H_;

    // one-time stage: Eq tile + wl
    *(float4*)(&eqs[tid * 4])        = *(const float4*)(qpb + tid * 4);
    *(float4*)(&eqs[1024 + tid * 4]) = *(const float4*)(qpb + 1024 + tid * 4);
    if (tid < 64) *(float4*)(&wls[tid * 4]) = *(const float4*)(wl + tid * 4);

    const float* kst = kpb + (size_t)m * H_ + 8 * qh;  // lane stages row m, 8 h
    float4 a0 = *(const float4*)(kst);
    float4 a1 = *(const float4*)(kst + 4);
    *(float4*)(&kq[0][2 * qh + 0][m][0]) = a0;
    *(float4*)(&kq[0][2 * qh + 1][m][0]) = a1;
    __syncthreads();

    float acc[4] = {0.f, 0.f, 0.f, 0.f};

    for (int c = 0; c < 16; ++c) {
        if (c < 15) {
            a0 = *(const float4*)(kst + (c + 1) * 16);
            a1 = *(const float4*)(kst + (c + 1) * 16 + 4);
        }
        const int buf = c & 1;
        const int h0 = c * 16;
#pragma unroll
        for (int quad = 0; quad < 4; ++quad) {
            float4 k4 = *(const float4*)(&kq[buf][quad][m][0]);
            float4 w4 = *(const float4*)(&wls[h0 + quad * 4]);
#pragma unroll
            for (int j2 = 0; j2 < 4; ++j2) {
                float4 q4 = *(const float4*)(&eqs[(qh * 4 + j2) * 256 + h0 + quad * 4]);
                float p0 = fmaf(k4.x, q4.x, 1.0f);
                float p1 = fmaf(k4.y, q4.y, 1.0f);
                float p2 = fmaf(k4.z, q4.z, 1.0f);
                float p3 = fmaf(k4.w, q4.w, 1.0f);
                float p01 = p0 * p1, p23 = p2 * p3;
                float n01 = fmaf(w4.y, p0, w4.x * p1);
                float n23 = fmaf(w4.w, p2, w4.z * p3);
                float Nm  = fmaf(n23, p01, n01 * p23);
                float P   = p01 * p23;
                acc[j2] = fmaf(Nm, __builtin_amdgcn_rcpf(P), acc[j2]);
            }
        }
        if (c < 15) {
            *(float4*)(&kq[buf ^ 1][2 * qh + 0][m][0]) = a0;
            *(float4*)(&kq[buf ^ 1][2 * qh + 1][m][0]) = a1;
            __syncthreads();
        }
    }

    // u = exp2(-2*log2e * sr), masked -> 0 (mask depends only on m)
    const float N2L = -2.885390081777926815f;   // -2*log2(e)
    const int mk = mcan[b * ML_ + mt * 128 + m];
    float u[4];
#pragma unroll
    for (int j2 = 0; j2 < 4; ++j2) {
        u[j2] = mk ? 0.f : __builtin_amdgcn_exp2f(N2L * acc[j2]);
        wout[((size_t)(b * QL_ + qt * 8 + qh * 4 + j2)) * ML_ + mt * 128 + m] = u[j2];
    }

    // partial row sums over this 128-m strip (deterministic, no atomics)
    float r[4] = {u[0], u[1], u[2], u[3]};
#pragma unroll
    for (int off = 32; off >= 1; off >>= 1) {
#pragma unroll
        for (int j2 = 0; j2 < 4; ++j2)
            r[j2] += __shfl_xor(r[j2], off);
    }
    if ((tid & 63) == 0) {
#pragma unroll
        for (int j2 = 0; j2 < 4; ++j2)
            sred[tid >> 6][j2] = r[j2];
    }
    __syncthreads();
    if (tid < 8) {
        const int q = tid;
        float v = sred[(q >> 2) * 2][q & 3] + sred[(q >> 2) * 2 + 1][q & 3];
        psum[((size_t)(b * QL_ + qt * 8 + q)) * 8 + mt] = v;
    }
}

// ---------------------------------------------------------------------------
// attns[b] = (u[b] @ M[b]) * inv_rowsum. LDS-tiled GEMM, epilogue-normalized.
// ---------------------------------------------------------------------------
__global__ __launch_bounds__(256) void attn_out_kernel(
    const float* __restrict__ wgt, const float* __restrict__ mem,
    const float* __restrict__ psum, float* __restrict__ out) {
    const int bid = blockIdx.x;
    const int b  = bid & 7;
    const int j2 = bid >> 3;
    const int mt = j2 & 3;
    const int nt = j2 >> 2;
    const int t = threadIdx.x;
    __shared__ float As[32][34];
    __shared__ float Bs[32][64];

    const int ar = t >> 3, ac = (t & 7) << 2;
    const int br = t >> 4, bc = (t & 15) << 2;
    const float* Ap = wgt + ((size_t)(b * QL_ + mt * 32 + ar)) * ML_ + ac;
    const float* Bp = mem + ((size_t)(b * ML_ + br)) * KS_ + nt * 64 + bc;

    const int tx = t & 15, ty = t >> 4;
    float acc0[4] = {0.f, 0.f, 0.f, 0.f};
    float acc1[4] = {0.f, 0.f, 0.f, 0.f};

    float4 apre = *(const float4*)(Ap);
    float4 bpre0 = *(const float4*)(Bp);
    float4 bpre1 = *(const float4*)(Bp + (size_t)16 * KS_);

    for (int k0 = 0; k0 < ML_; k0 += 32) {
        __syncthreads();
        As[ac + 0][ar] = apre.x; As[ac + 1][ar] = apre.y;
        As[ac + 2][ar] = apre.z; As[ac + 3][ar] = apre.w;
        *(float4*)(&Bs[br][bc])      = bpre0;
        *(float4*)(&Bs[br + 16][bc]) = bpre1;
        __syncthreads();
        if (k0 + 32 < ML_) {
            apre  = *(const float4*)(Ap + k0 + 32);
            bpre0 = *(const float4*)(Bp + (size_t)(k0 + 32) * KS_);
            bpre1 = *(const float4*)(Bp + (size_t)(k0 + 48) * KS_);
        }
#pragma unroll
        for (int kk = 0; kk < 32; ++kk) {
            float2 a2 = *(const float2*)(&As[kk][ty * 2]);
            float4 b4 = *(const float4*)(&Bs[kk][tx * 4]);
            acc0[0] = fmaf(a2.x, b4.x, acc0[0]);
            acc0[1] = fmaf(a2.x, b4.y, acc0[1]);
            acc0[2] = fmaf(a2.x, b4.z, acc0[2]);
            acc0[3] = fmaf(a2.x, b4.w, acc0[3]);
            acc1[0] = fmaf(a2.y, b4.x, acc1[0]);
            acc1[1] = fmaf(a2.y, b4.y, acc1[1]);
            acc1[2] = fmaf(a2.y, b4.z, acc1[2]);
            acc1[3] = fmaf(a2.y, b4.w, acc1[3]);
        }
    }
    // epilogue: normalize by row sums (8 partials per row, block-uniform rows)
    const float* ps = psum + ((size_t)(b * QL_ + mt * 32 + ty * 2)) * 8;
    float rs0 = 0.f, rs1 = 0.f;
#pragma unroll
    for (int i = 0; i < 8; ++i) { rs0 += ps[i]; rs1 += ps[8 + i]; }
    float inv0 = __builtin_amdgcn_rcpf(rs0);
    float inv1 = __builtin_amdgcn_rcpf(rs1);

    size_t orow = ((size_t)(b * QL_ + mt * 32 + ty * 2)) * KS_ + nt * 64 + tx * 4;
    *(float4*)(out + orow)       = make_float4(acc0[0] * inv0, acc0[1] * inv0,
                                               acc0[2] * inv0, acc0[3] * inv0);
    *(float4*)(out + orow + KS_) = make_float4(acc1[0] * inv1, acc1[1] * inv1,
                                               acc1[2] * inv1, acc1[3] * inv1);
}

// ---------------------------------------------------------------------------
// Normalize the weights output in place (runs AFTER attn_out consumed u).
// ---------------------------------------------------------------------------
__global__ __launch_bounds__(256) void scale_weights(
    float* __restrict__ wout, const float* __restrict__ psum) {
    const int row = blockIdx.x;          // b*QL + q
    const int tid = threadIdx.x;
    const float* ps = psum + (size_t)row * 8;
    float rs = ((ps[0] + ps[1]) + (ps[2] + ps[3])) +
               ((ps[4] + ps[5]) + (ps[6] + ps[7]));
    float inv = __builtin_amdgcn_rcpf(rs);
    float4* p = (float4*)(wout + (size_t)row * ML_ + tid * 4);
    float4 v = *p;
    *p = make_float4(v.x * inv, v.y * inv, v.z * inv, v.w * inv);
}

extern "C" void kernel_launch(void* const* d_in, const int* in_sizes, int n_in,
                              void* d_out, int out_size, void* d_ws, size_t ws_size,
                              hipStream_t stream) {
    const float* query  = (const float*)d_in[0];
    const float* memory = (const float*)d_in[1];
    const unsigned char* mask = (const unsigned char*)d_in[2];
    const float* Wq = (const float*)d_in[3];
    const float* bq = (const float*)d_in[4];
    const float* Wk = (const float*)d_in[5];
    const float* bk = (const float*)d_in[6];
    const float* wl = (const float*)d_in[7];
    // d_in[8] (bl) cancels under softmax shift-invariance; not read.

    float* ws = (float*)d_ws;
    float* Eq = ws + QP_OFF;
    float* Ek = ws + KP_OFF;
    unsigned char* mcan = (unsigned char*)(ws + MASK_OFF);
    float* psum = ws + PSUM_OFF;

    float* attns = (float*)d_out;                      // [B][QL][KS]
    float* wout  = (float*)d_out + B_ * QL_ * KS_;     // [B][QL][ML]: u, then weights

    proj_kernel<<<dim3(2305), dim3(64), 0, stream>>>(query, memory, Wq, bq, Wk, bk,
                                                     Eq, Ek, mask, mcan);
    logits_kernel<<<dim3(1024), dim3(256), 0, stream>>>(Eq, Ek, wl, mcan, wout, psum);
    attn_out_kernel<<<dim3(256), dim3(256), 0, stream>>>(wout, memory, psum, attns);
    scale_weights<<<dim3(B_ * QL_), dim3(256), 0, stream>>>(wout, psum);
}